// Round 1
// baseline (418.869 us; speedup 1.0000x reference)
//
#include <hip/hip_runtime.h>

using u32 = unsigned int;

// ---------------- workspace layout (bytes) ----------------
constexpr int  N_IMG   = 16;
constexpr int  PADROW  = 4096;          // 64 cols * 64 ch bytes
constexpr int  ROWS_PI = 58;            // 56 real + top/bottom pad rows
constexpr size_t OFS_QX  = 4096;
constexpr size_t SZ_QPAD = (size_t)(1 + N_IMG * ROWS_PI) * PADROW;   // 3,805,184
constexpr size_t OFS_Q1  = OFS_QX + SZ_QPAD;
constexpr size_t OFS_O1  = OFS_Q1 + SZ_QPAD;
constexpr size_t SZ_OF   = (size_t)N_IMG * 56 * 56 * 64 * 4;         // 12,845,056
constexpr size_t OFS_O2  = OFS_O1 + SZ_OF;
constexpr size_t OFS_QW1 = OFS_O2 + SZ_OF;
constexpr size_t OFS_QW2 = OFS_QW1 + 36864;
constexpr size_t OFS_WB1 = OFS_QW2 + 36864;
constexpr size_t OFS_WB2 = OFS_WB1 + 18432;
constexpr size_t OFS_WSUM= OFS_WB2 + 18432;
constexpr size_t OFS_STX = OFS_WSUM + 256;
constexpr size_t OFS_STQ = OFS_STX + 294912;
constexpr size_t WS_NEED = OFS_STQ + 294912;
constexpr size_t OUTN    = (size_t)16 * 64 * 56 * 56;                // 3,211,264

// dot4: int8x4 . int8x4 + c
static __device__ __forceinline__ int dot4i8(u32 a, u32 b, int c) {
#if defined(__has_builtin)
#if __has_builtin(__builtin_amdgcn_sdot4)
    return __builtin_amdgcn_sdot4((int)a, (int)b, c, false);
#else
    c += (int)(signed char)(a & 0xFF)        * (int)(signed char)(b & 0xFF);
    c += (int)(signed char)((a >> 8) & 0xFF) * (int)(signed char)((b >> 8) & 0xFF);
    c += (int)(signed char)((a >> 16) & 0xFF)* (int)(signed char)((b >> 16) & 0xFF);
    c += (int)(signed char)(a >> 24)         * (int)(signed char)(b >> 24);
    return c;
#endif
#else
    c += (int)(signed char)(a & 0xFF)        * (int)(signed char)(b & 0xFF);
    c += (int)(signed char)((a >> 8) & 0xFF) * (int)(signed char)((b >> 8) & 0xFF);
    c += (int)(signed char)((a >> 16) & 0xFF)* (int)(signed char)((b >> 16) & 0xFF);
    c += (int)(signed char)(a >> 24)         * (int)(signed char)(b >> 24);
    return c;
#endif
}

// ---------------- K0: zero the scalar accumulators ----------------
__global__ void k_init(float* scal) {
    if (threadIdx.x < 8) scal[threadIdx.x] = 0.f;
}

// ---------------- K1: absmax of x / w1 / w2 ----------------
__global__ __launch_bounds__(256) void k_absmax(const float* __restrict__ x,
                                                const float* __restrict__ w1,
                                                const float* __restrict__ w2,
                                                float* __restrict__ scal) {
    const float* p; int n; int slot;
    if (blockIdx.y == 0)      { p = x;  n = 16*64*56*56; slot = 0; }
    else if (blockIdx.y == 1) { p = w1; n = 64*64*9;     slot = 1; }
    else                      { p = w2; n = 64*64*9;     slot = 2; }
    float m = 0.f;
    for (int i = blockIdx.x * 256 + threadIdx.x; i < n; i += gridDim.x * 256)
        m = fmaxf(m, fabsf(p[i]));
    __shared__ float red[256];
    red[threadIdx.x] = m; __syncthreads();
    for (int s = 128; s > 0; s >>= 1) {
        if (threadIdx.x < s) red[threadIdx.x] = fmaxf(red[threadIdx.x], red[threadIdx.x + s]);
        __syncthreads();
    }
    if (threadIdx.x == 0) atomicMax((u32*)(scal + slot), __float_as_uint(red[0]));
}

// ---------------- K2: quantize x -> padded NHWC int8 ----------------
__global__ __launch_bounds__(256) void k_quant_x(const float* __restrict__ x,
                                                 char* __restrict__ qpad,
                                                 const float* __restrict__ scal) {
    int n = blockIdx.x, yy = blockIdx.y, t = threadIdx.x;
    u32* row = (u32*)(qpad + (size_t)(1 + n * ROWS_PI + yy) * PADROW);
    if (n == 0 && yy == 0) {                  // global leading zero row
        u32* r0 = (u32*)qpad;
        for (int j = t; j < 1024; j += 256) r0[j] = 0u;
    }
    if (yy == 0 || yy == 57) {                // per-image pad rows
        for (int j = t; j < 1024; j += 256) row[j] = 0u;
        return;
    }
    int y = yy - 1;
    float sx = scal[0] / 127.f;
    __shared__ char lq[4096];
    for (int idx = t; idx < 3584; idx += 256) {
        int c = idx / 56, xx = idx - c * 56;
        float v = x[(size_t)n * 200704 + (size_t)c * 3136 + y * 56 + xx];
        float q = rintf(v / sx);
        q = fminf(fmaxf(q, -127.f), 127.f);
        lq[xx * 64 + c] = (char)(int)q;
    }
    __syncthreads();
    u32* lqd = (u32*)lq;
    for (int j = t; j < 1024; j += 256) row[j] = (j < 896) ? lqd[j] : 0u;
}

// ---------------- K2b: quantize weights, WB bit-stats, per-co weight sum ----------------
// qw layout (bytes): ((kp*16 + ci/4)*64 + co)*4 + (ci&3)   [dword: (kp*16+d)*64+co]
__global__ void k_quant_w(const float* __restrict__ w1, const float* __restrict__ w2,
                          char* __restrict__ qw1, char* __restrict__ qw2,
                          int* __restrict__ wb1, int* __restrict__ wb2,
                          int* __restrict__ wsum, const float* __restrict__ scal) {
    int wsel = blockIdx.x;
    const float* w = wsel ? w2 : w1;
    char* qw = wsel ? qw2 : qw1;
    int* wb  = wsel ? wb2 : wb1;
    float s = scal[1 + wsel] / 127.f;
    int ci = threadIdx.x, kp = threadIdx.y;
    int bc[8] = {0,0,0,0,0,0,0,0};
    for (int co = 0; co < 64; co++) {
        float v = w[((size_t)co * 64 + ci) * 9 + kp];
        float qf = rintf(v / s);
        qf = fminf(fmaxf(qf, -127.f), 127.f);
        int q = (int)qf;
        qw[((kp * 16 + (ci >> 2)) * 64 + co) * 4 + (ci & 3)] = (char)q;
        u32 u = (u32)q & 0xFFu;
#pragma unroll
        for (int k = 0; k < 8; k++) bc[k] += (u >> k) & 1;
    }
#pragma unroll
    for (int k = 0; k < 8; k++) wb[(ci * 8 + k) * 9 + kp] = bc[k];
    __syncthreads();
    if (wsel == 1) {
        int tid = threadIdx.y * 64 + threadIdx.x;
        if (tid < 64) {     // wsum[co] = sum of all 576 int8 weights of output channel co
            const u32* q = (const u32*)qw2;
            int ssum = 0;
            for (int j = 0; j < 144; j++) {
                u32 v = q[j * 64 + tid];
                ssum += (int)(signed char)(v & 0xFF) + (int)(signed char)((v >> 8) & 0xFF)
                      + (int)(signed char)((v >> 16) & 0xFF) + (int)(signed char)(v >> 24);
            }
            wsum[tid] = ssum;
        }
    }
}

// ---------------- K3: per-(ci,bit) stats: T, border rows/cols, corners ----------------
// lst layout: j*512 + ci*8 + k ; j: 0=T 1=Rtop 2=Rbot 3=Cleft 4=Cright 5=(0,0) 6=(0,55) 7=(55,0) 8=(55,55)
__global__ __launch_bounds__(256) void k_stats(const char* __restrict__ qpad, u32 xorm,
                                               int* __restrict__ st) {
    int n = blockIdx.x, t = threadIdx.x;
    __shared__ int lst[4608];
    for (int i = t; i < 4608; i += 256) lst[i] = 0;
    __syncthreads();
    const u32* img = (const u32*)(qpad + (size_t)(2 + n * ROWS_PI) * PADROW); // real row 0
    u32 xm = xorm * 0x01010101u;
    int ci4 = t & 15, xo = t >> 4;
    u32 pk[8] = {0,0,0,0,0,0,0,0};
    for (int y = 0; y < 56; y++) {
        const u32* row = img + y * 1024;
#pragma unroll
        for (int j = 0; j < 4; j++) {
            int xx = xo + 16 * j;
            if (xx < 56) {
                u32 v = row[xx * 16 + ci4] ^ xm;
#pragma unroll
                for (int k = 0; k < 8; k++) pk[k] += (v >> k) & 0x01010101u;
            }
        }
    }
#pragma unroll
    for (int k = 0; k < 8; k++)
#pragma unroll
        for (int b = 0; b < 4; b++) {
            int cnt = (pk[k] >> (8 * b)) & 0xFF;
            atomicAdd(&lst[(ci4 * 4 + b) * 8 + k], cnt);
        }
    // border rows y=0 (j=1), y=55 (j=2)
    for (int i = t; i < 2048; i += 256) {
        int half = i >> 10, idx = i & 1023;
        int xx = idx >> 4, c4 = idx & 15;
        if (xx < 56) {
            int y = half ? 55 : 0;
            u32 v = img[y * 1024 + xx * 16 + c4] ^ xm;
            int jbase = (half ? 2 : 1) * 512;
            for (int b = 0; b < 4; b++)
                for (int k = 0; k < 8; k++)
                    if ((v >> (8 * b + k)) & 1) atomicAdd(&lst[jbase + (c4 * 4 + b) * 8 + k], 1);
        }
    }
    // border cols x=0 (j=3), x=55 (j=4)
    for (int i = t; i < 1792; i += 256) {
        int side = i / 896, r = i - side * 896;
        int y = r >> 4, c4 = r & 15;
        int xx = side ? 55 : 0;
        u32 v = img[y * 1024 + xx * 16 + c4] ^ xm;
        int jbase = (side ? 4 : 3) * 512;
        for (int b = 0; b < 4; b++)
            for (int k = 0; k < 8; k++)
                if ((v >> (8 * b + k)) & 1) atomicAdd(&lst[jbase + (c4 * 4 + b) * 8 + k], 1);
    }
    // corners j=5..8
    if (t < 64) {
        int corner = t >> 4, c4 = t & 15;
        int y = (corner & 2) ? 55 : 0;
        int xx = (corner & 1) ? 55 : 0;
        u32 v = img[y * 1024 + xx * 16 + c4] ^ xm;
        int jbase = (5 + corner) * 512;
        for (int b = 0; b < 4; b++)
            for (int k = 0; k < 8; k++)
                if ((v >> (8 * b + k)) & 1) atomicAdd(&lst[jbase + (c4 * 4 + b) * 8 + k], 1);
    }
    __syncthreads();
    for (int i = t; i < 4608; i += 256) st[n * 4608 + i] = lst[i];
}

// ---------------- K5/K7: int8 conv 3x3, bn epilogue, relu-max ----------------
template <int SECOND>
__global__ __launch_bounds__(256) void k_conv(const char* __restrict__ qin,
                                              const char* __restrict__ qw,
                                              const int* __restrict__ wsum,
                                              const char* __restrict__ qid,
                                              const float* __restrict__ g, const float* __restrict__ b,
                                              const float* __restrict__ m, const float* __restrict__ v,
                                              const float* __restrict__ scal,
                                              float* __restrict__ outp, float* __restrict__ rmax) {
    __shared__ __align__(16) u32 lw[9216];     // [kp*16+d][co]
    __shared__ __align__(16) u32 lin[2784];    // [ky][58 px][16 dwords]
    __shared__ float red[256];
    int n = blockIdx.x, y = blockIdx.y, t = threadIdx.x;
    int co = t & 63, xg = t >> 6;
    const u32* qwd = (const u32*)qw;
    for (int gi = t; gi < 9216; gi += 256) lw[gi] = qwd[gi];
    const u32* qind = (const u32*)qin;
    size_t imgdw = (size_t)(1 + n * ROWS_PI) * 1024;
    for (int gi = t; gi < 2784; gi += 256) {
        int ky = gi / 928, j = gi - ky * 928;
        lin[gi] = qind[imgdw + (size_t)(y + ky) * 1024 - 16 + j];
    }
    __syncthreads();

    int acc[14];
#pragma unroll
    for (int i = 0; i < 14; i++) acc[i] = 0;
#pragma unroll 1
    for (int ch = 0; ch < 4; ch++) {
        u32 wr[36];
#pragma unroll
        for (int kp = 0; kp < 9; kp++)
#pragma unroll
            for (int dd = 0; dd < 4; dd++)
                wr[kp * 4 + dd] = lw[(kp * 16 + ch * 4 + dd) * 64 + co];
#pragma unroll
        for (int i = 0; i < 14; i++) {
            int x = xg * 14 + i;
#pragma unroll
            for (int ky = 0; ky < 3; ky++) {
#pragma unroll
                for (int kx = 0; kx < 3; kx++) {
                    const uint4 iv = *(const uint4*)&lin[ky * 928 + (x + kx) * 16 + ch * 4];
                    int kp4 = (ky * 3 + kx) * 4;
                    acc[i] = dot4i8(iv.x, wr[kp4 + 0], acc[i]);
                    acc[i] = dot4i8(iv.y, wr[kp4 + 1], acc[i]);
                    acc[i] = dot4i8(iv.z, wr[kp4 + 2], acc[i]);
                    acc[i] = dot4i8(iv.w, wr[kp4 + 3], acc[i]);
                }
            }
        }
    }
    // epilogue
    float inv = g[co] * rsqrtf(v[co] + 1e-5f);
    float sIn = SECOND ? scal[3] / 255.f : scal[0] / 127.f;
    float sW  = SECOND ? scal[2] / 127.f : scal[1] / 127.f;
    float alpha = sIn * sW * inv;
    float beta = b[co] - m[co] * inv;
    int wofs = SECOND ? (wsum[co] << 7) : 0;
    float sx = scal[0] / 127.f;
    float lmax = 0.f;
    size_t rowb = (size_t)(n * 56 + y) * 3584;
    const signed char* idrow = SECOND ? (const signed char*)(qid + (size_t)(2 + n * ROWS_PI + y) * PADROW)
                                      : (const signed char*)nullptr;
#pragma unroll
    for (int i = 0; i < 14; i++) {
        int x = xg * 14 + i;
        float o = (float)(acc[i] + wofs) * alpha + beta;
        if (SECOND) o += sx * (float)idrow[x * 64 + co];
        outp[rowb + x * 64 + co] = o;
        lmax = fmaxf(lmax, o);
    }
    red[t] = lmax; __syncthreads();
    for (int s = 128; s > 0; s >>= 1) {
        if (t < s) red[t] = fmaxf(red[t], red[t + s]);
        __syncthreads();
    }
    if (t == 0) atomicMax((u32*)rmax, __float_as_uint(red[0]));
}

// ---------------- K6: quantize conv1 output -> q1-128 padded int8 ----------------
__global__ __launch_bounds__(256) void k_quant_relu1(const float* __restrict__ of,
                                                     char* __restrict__ qpad,
                                                     const float* __restrict__ scal) {
    int n = blockIdx.x, yy = blockIdx.y, t = threadIdx.x;
    u32* row = (u32*)(qpad + (size_t)(1 + n * ROWS_PI + yy) * PADROW);
    if (n == 0 && yy == 0) {
        u32* r0 = (u32*)qpad;
        for (int j = t; j < 1024; j += 256) r0[j] = 0x80808080u;
    }
    if (yy == 0 || yy == 57) {
        for (int j = t; j < 1024; j += 256) row[j] = 0x80808080u;
        return;
    }
    int y = yy - 1;
    float s1 = scal[3] / 255.f;
    char* rowb = (char*)row;
    const float* orow = of + (size_t)(n * 56 + y) * 3584;
    for (int idx = t; idx < 3584; idx += 256) {
        float vv = fmaxf(orow[idx], 0.f);
        float q = fminf(rintf(vv / s1), 255.f);
        rowb[idx] = (char)((int)q - 128);
    }
    for (int j = 896 + t; j < 1024; j += 256) row[j] = 0x80808080u;
}

// ---------------- K8: final quantize + NHWC->NCHW transpose ----------------
__global__ __launch_bounds__(256) void k_final(const float* __restrict__ of,
                                               const float* __restrict__ scal,
                                               float* __restrict__ outp) {
    int n = blockIdx.x, y = blockIdx.y, t = threadIdx.x;
    __shared__ float lt[64 * 57];
    float s2 = scal[4] / 255.f;
    const float* orow = of + (size_t)(n * 56 + y) * 3584;
    for (int idx = t; idx < 3584; idx += 256) {
        int co = idx & 63, xx = idx >> 6;
        float vv = fmaxf(orow[idx], 0.f);
        float q = fminf(rintf(vv / s2), 255.f);
        lt[co * 57 + xx] = q * s2;
    }
    __syncthreads();
    for (int idx = t; idx < 3584; idx += 256) {
        int co = idx / 56, xx = idx - co * 56;
        outp[(size_t)n * 200704 + (size_t)co * 3136 + y * 56 + xx] = lt[co * 57 + xx];
    }
}

// ---------------- K9: combine bit-stats into HM_act / HM_energy ----------------
__global__ __launch_bounds__(512) void k_hm(const int* __restrict__ stx, const int* __restrict__ stq,
                                            const int* __restrict__ wb1, const int* __restrict__ wb2,
                                            float* __restrict__ outp) {
    int t = threadIdx.x;   // t = ci*8 + k
    long long act = 0, en = 0;
#pragma unroll
    for (int w = 0; w < 2; w++) {
        const int* st = w ? stq : stx;
        const int* wb = w ? wb2 : wb1;
        long long s[9];
        for (int j = 0; j < 9; j++) {
            long long a = 0;
            for (int n = 0; n < 16; n++) a += st[n * 4608 + j * 512 + t];
            s[j] = a;
        }
        const int* wrow = wb + t * 9;
        int w0 = wrow[0], w1_ = wrow[1], w2_ = wrow[2], w3 = wrow[3], w4 = wrow[4],
            w5 = wrow[5], w6 = wrow[6], w7 = wrow[7], w8 = wrow[8];
        long long wall = (long long)w0 + w1_ + w2_ + w3 + w4 + w5 + w6 + w7 + w8;
        long long wr0 = (long long)w0 + w1_ + w2_;       // ky=0 row
        long long wr2 = (long long)w6 + w7 + w8;         // ky=2 row
        long long wc0 = (long long)w0 + w3 + w6;         // kx=0 col
        long long wc2 = (long long)w2_ + w5 + w8;        // kx=2 col
        en += s[0] * wall - s[1] * wr2 - s[2] * wr0 - s[3] * wc2 - s[4] * wc0
            + s[5] * w8 + s[6] * w6 + s[7] * w2_ + s[8] * w0;
        act += s[0];
    }
    __shared__ long long r1[512];
    r1[t] = en; __syncthreads();
    for (int s = 256; s > 0; s >>= 1) { if (t < s) r1[t] += r1[t + s]; __syncthreads(); }
    long long etot = r1[0]; __syncthreads();
    r1[t] = act; __syncthreads();
    for (int s = 256; s > 0; s >>= 1) { if (t < s) r1[t] += r1[t + s]; __syncthreads(); }
    if (t == 0) {
        outp[OUTN]     = (float)r1[0];   // HM_act
        outp[OUTN + 1] = (float)etot;    // HM_energy
    }
}

extern "C" void kernel_launch(void* const* d_in, const int* in_sizes, int n_in,
                              void* d_out, int out_size, void* d_ws, size_t ws_size,
                              hipStream_t stream) {
    if (ws_size < WS_NEED) return;
    const float* x  = (const float*)d_in[0];
    const float* w1 = (const float*)d_in[1];
    const float* w2 = (const float*)d_in[2];
    const float* g1 = (const float*)d_in[3];
    const float* b1 = (const float*)d_in[4];
    const float* m1 = (const float*)d_in[5];
    const float* v1 = (const float*)d_in[6];
    const float* g2 = (const float*)d_in[7];
    const float* b2 = (const float*)d_in[8];
    const float* m2 = (const float*)d_in[9];
    const float* v2 = (const float*)d_in[10];
    char* ws = (char*)d_ws;
    float* scal = (float*)ws;
    char* qx = ws + OFS_QX;
    char* q1 = ws + OFS_Q1;
    float* o1 = (float*)(ws + OFS_O1);
    float* o2 = (float*)(ws + OFS_O2);
    char* qw1 = ws + OFS_QW1;
    char* qw2 = ws + OFS_QW2;
    int* wb1 = (int*)(ws + OFS_WB1);
    int* wb2 = (int*)(ws + OFS_WB2);
    int* wsum = (int*)(ws + OFS_WSUM);
    int* stx = (int*)(ws + OFS_STX);
    int* stq = (int*)(ws + OFS_STQ);
    float* outp = (float*)d_out;

    k_init<<<1, 64, 0, stream>>>(scal);
    k_absmax<<<dim3(1024, 3), 256, 0, stream>>>(x, w1, w2, scal);
    k_quant_x<<<dim3(16, 58), 256, 0, stream>>>(x, qx, scal);
    k_quant_w<<<2, dim3(64, 9), 0, stream>>>(w1, w2, qw1, qw2, wb1, wb2, wsum, scal);
    k_stats<<<16, 256, 0, stream>>>(qx, 0u, stx);
    k_conv<0><<<dim3(16, 56), 256, 0, stream>>>(qx, qw1, nullptr, nullptr,
                                                g1, b1, m1, v1, scal, o1, scal + 3);
    k_quant_relu1<<<dim3(16, 58), 256, 0, stream>>>(o1, q1, scal);
    k_stats<<<16, 256, 0, stream>>>(q1, 0x80u, stq);
    k_conv<1><<<dim3(16, 56), 256, 0, stream>>>(q1, qw2, wsum, qx,
                                                g2, b2, m2, v2, scal, o2, scal + 4);
    k_final<<<dim3(16, 56), 256, 0, stream>>>(o2, scal, outp);
    k_hm<<<1, 512, 0, stream>>>(stx, stq, wb1, wb2, outp);
}

// Round 2
// 271.503 us; speedup vs baseline: 1.5428x; 1.5428x over previous
//
#include <hip/hip_runtime.h>

using u32 = unsigned int;

// ---------------- workspace layout (bytes) ----------------
constexpr int  N_IMG   = 16;
constexpr int  PADROW  = 4096;          // 64 cols * 64 ch bytes
constexpr int  ROWS_PI = 58;            // 56 real + top/bottom pad rows
constexpr size_t OFS_QX  = 4096;
constexpr size_t SZ_QPAD = (size_t)(1 + N_IMG * ROWS_PI) * PADROW;   // 3,805,184
constexpr size_t OFS_Q1  = OFS_QX + SZ_QPAD;
constexpr size_t OFS_O1  = OFS_Q1 + SZ_QPAD;
constexpr size_t SZ_OF   = (size_t)N_IMG * 56 * 56 * 64 * 4;         // 12,845,056
constexpr size_t OFS_O2  = OFS_O1 + SZ_OF;
constexpr size_t OFS_QW1 = OFS_O2 + SZ_OF;
constexpr size_t OFS_QW2 = OFS_QW1 + 36864;
constexpr size_t OFS_WB1 = OFS_QW2 + 36864;
constexpr size_t OFS_WB2 = OFS_WB1 + 18432;
constexpr size_t OFS_WSUM= OFS_WB2 + 18432;
constexpr size_t OFS_STX = OFS_WSUM + 256;      // 4608 ints (aggregated over images)
constexpr size_t OFS_STQ = OFS_STX + 294912;
constexpr size_t WS_NEED = OFS_STQ + 294912;
constexpr size_t OUTN    = (size_t)16 * 64 * 56 * 56;                // 3,211,264

// dot4: int8x4 . int8x4 + c
static __device__ __forceinline__ int dot4i8(u32 a, u32 b, int c) {
#if defined(__has_builtin)
#if __has_builtin(__builtin_amdgcn_sdot4)
    return __builtin_amdgcn_sdot4((int)a, (int)b, c, false);
#else
    c += (int)(signed char)(a & 0xFF)        * (int)(signed char)(b & 0xFF);
    c += (int)(signed char)((a >> 8) & 0xFF) * (int)(signed char)((b >> 8) & 0xFF);
    c += (int)(signed char)((a >> 16) & 0xFF)* (int)(signed char)((b >> 16) & 0xFF);
    c += (int)(signed char)(a >> 24)         * (int)(signed char)(b >> 24);
    return c;
#endif
#else
    c += (int)(signed char)(a & 0xFF)        * (int)(signed char)(b & 0xFF);
    c += (int)(signed char)((a >> 8) & 0xFF) * (int)(signed char)((b >> 8) & 0xFF);
    c += (int)(signed char)((a >> 16) & 0xFF)* (int)(signed char)((b >> 16) & 0xFF);
    c += (int)(signed char)(a >> 24)         * (int)(signed char)(b >> 24);
    return c;
#endif
}

// ---------------- K0: zero scalars + aggregated stats ----------------
__global__ __launch_bounds__(256) void k_init(float* scal, int* gstx, int* gstq) {
    int i = blockIdx.x * 256 + threadIdx.x;
    if (i < 8) scal[i] = 0.f;
    if (i < 4608) { gstx[i] = 0; gstq[i] = 0; }
}

// ---------------- K1: absmax of x / w1 / w2 ----------------
__global__ __launch_bounds__(256) void k_absmax(const float* __restrict__ x,
                                                const float* __restrict__ w1,
                                                const float* __restrict__ w2,
                                                float* __restrict__ scal) {
    const float* p; int n; int slot;
    if (blockIdx.y == 0)      { p = x;  n = 16*64*56*56; slot = 0; }
    else if (blockIdx.y == 1) { p = w1; n = 64*64*9;     slot = 1; }
    else                      { p = w2; n = 64*64*9;     slot = 2; }
    float m = 0.f;
    for (int i = blockIdx.x * 256 + threadIdx.x; i < n; i += gridDim.x * 256)
        m = fmaxf(m, fabsf(p[i]));
    __shared__ float red[256];
    red[threadIdx.x] = m; __syncthreads();
    for (int s = 128; s > 0; s >>= 1) {
        if (threadIdx.x < s) red[threadIdx.x] = fmaxf(red[threadIdx.x], red[threadIdx.x + s]);
        __syncthreads();
    }
    if (threadIdx.x == 0) atomicMax((u32*)(scal + slot), __float_as_uint(red[0]));
}

// ---------------- K2: quantize x -> padded NHWC int8 ----------------
__global__ __launch_bounds__(256) void k_quant_x(const float* __restrict__ x,
                                                 char* __restrict__ qpad,
                                                 const float* __restrict__ scal) {
    int n = blockIdx.x, yy = blockIdx.y, t = threadIdx.x;
    u32* row = (u32*)(qpad + (size_t)(1 + n * ROWS_PI + yy) * PADROW);
    if (n == 0 && yy == 0) {                  // global leading zero row
        u32* r0 = (u32*)qpad;
        for (int j = t; j < 1024; j += 256) r0[j] = 0u;
    }
    if (yy == 0 || yy == 57) {                // per-image pad rows
        for (int j = t; j < 1024; j += 256) row[j] = 0u;
        return;
    }
    int y = yy - 1;
    float sx = scal[0] / 127.f;
    __shared__ char lq[4096];
    for (int idx = t; idx < 3584; idx += 256) {
        int c = idx / 56, xx = idx - c * 56;
        float v = x[(size_t)n * 200704 + (size_t)c * 3136 + y * 56 + xx];
        float q = rintf(v / sx);
        q = fminf(fmaxf(q, -127.f), 127.f);
        lq[xx * 64 + c] = (char)(int)q;
    }
    __syncthreads();
    u32* lqd = (u32*)lq;
    for (int j = t; j < 1024; j += 256) row[j] = (j < 896) ? lqd[j] : 0u;
}

// ---------------- K2b: quantize weights, WB bit-stats, per-co weight sum ----------------
__global__ void k_quant_w(const float* __restrict__ w1, const float* __restrict__ w2,
                          char* __restrict__ qw1, char* __restrict__ qw2,
                          int* __restrict__ wb1, int* __restrict__ wb2,
                          int* __restrict__ wsum, const float* __restrict__ scal) {
    int wsel = blockIdx.x;
    const float* w = wsel ? w2 : w1;
    char* qw = wsel ? qw2 : qw1;
    int* wb  = wsel ? wb2 : wb1;
    float s = scal[1 + wsel] / 127.f;
    int ci = threadIdx.x, kp = threadIdx.y;
    int bc[8] = {0,0,0,0,0,0,0,0};
    for (int co = 0; co < 64; co++) {
        float v = w[((size_t)co * 64 + ci) * 9 + kp];
        float qf = rintf(v / s);
        qf = fminf(fmaxf(qf, -127.f), 127.f);
        int q = (int)qf;
        qw[((kp * 16 + (ci >> 2)) * 64 + co) * 4 + (ci & 3)] = (char)q;
        u32 u = (u32)q & 0xFFu;
#pragma unroll
        for (int k = 0; k < 8; k++) bc[k] += (u >> k) & 1;
    }
#pragma unroll
    for (int k = 0; k < 8; k++) wb[(ci * 8 + k) * 9 + kp] = bc[k];
    __syncthreads();
    if (wsel == 1) {
        int tid = threadIdx.y * 64 + threadIdx.x;
        if (tid < 64) {
            const u32* q = (const u32*)qw2;
            int ssum = 0;
            for (int j = 0; j < 144; j++) {
                u32 v = q[j * 64 + tid];
                ssum += (int)(signed char)(v & 0xFF) + (int)(signed char)((v >> 8) & 0xFF)
                      + (int)(signed char)((v >> 16) & 0xFF) + (int)(signed char)(v >> 24);
            }
            wsum[tid] = ssum;
        }
    }
}

// ---------------- K3: bit stats via packed counters, no LDS atomics ----------------
// gst layout: j*512 + ci*8 + k ; j: 0=T 1=Rtop 2=Rbot 3=Cleft 4=Cright 5=(0,0) 6=(0,55) 7=(55,0) 8=(55,55)
// Aggregated over all 16 images (global atomicAdd).
static __device__ __forceinline__ void unpack_acc(u32 v, u32 pk[8]) {
#pragma unroll
    for (int k = 0; k < 8; k++) pk[k] += (v >> k) & 0x01010101u;
}

// red: LDS u32[2048], layout red[k*256 + t]
static __device__ __forceinline__ void reduce_cat(u32* red, int* gdst, const u32 pk[8],
                                                  bool active, int t) {
#pragma unroll
    for (int k = 0; k < 8; k++) red[k * 256 + t] = active ? pk[k] : 0u;
    __syncthreads();
#pragma unroll
    for (int p = t; p < 512; p += 256) {
        int ci = p >> 3, k = p & 7, ci4 = ci >> 2, b = ci & 3;
        int sum = 0;
#pragma unroll
        for (int xo = 0; xo < 16; xo++)
            sum += (red[k * 256 + xo * 16 + ci4] >> (8 * b)) & 0xFF;
        if (sum) atomicAdd(&gdst[p], sum);
    }
    __syncthreads();
}

__global__ __launch_bounds__(256) void k_stats(const char* __restrict__ qpad, u32 xorm,
                                               int* __restrict__ gst) {
    int n = blockIdx.x, slab = blockIdx.y, t = threadIdx.x;
    int ci4 = t & 15, xo = t >> 4;
    const u32* img = (const u32*)(qpad + (size_t)(2 + n * ROWS_PI) * PADROW); // real row 0
    u32 xm = xorm * 0x01010101u;
    __shared__ u32 red[2048];
    int y0 = slab * 4;

    // main total (j=0)
    {
        u32 pk[8] = {0,0,0,0,0,0,0,0};
#pragma unroll
        for (int r = 0; r < 4; r++) {
            const u32* row = img + (size_t)(y0 + r) * 1024;
#pragma unroll
            for (int j = 0; j < 4; j++) {
                int xx = xo + 16 * j;
                if (xx < 56) unpack_acc(row[xx * 16 + ci4] ^ xm, pk);
            }
        }
        reduce_cat(red, gst + 0 * 512, pk, true, t);
    }
    // Cleft (j=3): x == 0
    {
        u32 pk[8] = {0,0,0,0,0,0,0,0};
        bool act = (xo == 0);
        if (act)
#pragma unroll
            for (int r = 0; r < 4; r++)
                unpack_acc(img[(size_t)(y0 + r) * 1024 + ci4] ^ xm, pk);
        reduce_cat(red, gst + 3 * 512, pk, act, t);
    }
    // Cright (j=4): x == 55
    {
        u32 pk[8] = {0,0,0,0,0,0,0,0};
        bool act = (xo == 7);
        if (act)
#pragma unroll
            for (int r = 0; r < 4; r++)
                unpack_acc(img[(size_t)(y0 + r) * 1024 + 55 * 16 + ci4] ^ xm, pk);
        reduce_cat(red, gst + 4 * 512, pk, act, t);
    }
    if (slab == 0) {   // Rtop (j=1) + corners (0,0)->5, (0,55)->6
        u32 pk[8] = {0,0,0,0,0,0,0,0};
#pragma unroll
        for (int j = 0; j < 4; j++) {
            int xx = xo + 16 * j;
            if (xx < 56) unpack_acc(img[xx * 16 + ci4] ^ xm, pk);
        }
        reduce_cat(red, gst + 1 * 512, pk, true, t);
        if (t < 32) {
            int which = t >> 4, c4 = t & 15;
            u32 v = img[(which ? 55 : 0) * 16 + c4] ^ xm;
            for (int b = 0; b < 4; b++)
                for (int k = 0; k < 8; k++)
                    if ((v >> (8 * b + k)) & 1)
                        atomicAdd(&gst[(5 + which) * 512 + (c4 * 4 + b) * 8 + k], 1);
        }
    }
    if (slab == 13) {  // Rbot (j=2) + corners (55,0)->7, (55,55)->8
        u32 pk[8] = {0,0,0,0,0,0,0,0};
#pragma unroll
        for (int j = 0; j < 4; j++) {
            int xx = xo + 16 * j;
            if (xx < 56) unpack_acc(img[(size_t)55 * 1024 + xx * 16 + ci4] ^ xm, pk);
        }
        reduce_cat(red, gst + 2 * 512, pk, true, t);
        if (t < 32) {
            int which = t >> 4, c4 = t & 15;
            u32 v = img[(size_t)55 * 1024 + (which ? 55 : 0) * 16 + c4] ^ xm;
            for (int b = 0; b < 4; b++)
                for (int k = 0; k < 8; k++)
                    if ((v >> (8 * b + k)) & 1)
                        atomicAdd(&gst[(7 + which) * 512 + (c4 * 4 + b) * 8 + k], 1);
        }
    }
}

// ---------------- K5/K7: int8 conv 3x3, bn epilogue, relu-max ----------------
template <int SECOND>
__global__ __launch_bounds__(256) void k_conv(const char* __restrict__ qin,
                                              const char* __restrict__ qw,
                                              const int* __restrict__ wsum,
                                              const char* __restrict__ qid,
                                              const float* __restrict__ g, const float* __restrict__ b,
                                              const float* __restrict__ m, const float* __restrict__ v,
                                              const float* __restrict__ scal,
                                              float* __restrict__ outp, float* __restrict__ rmax) {
    __shared__ __align__(16) u32 lw[9216];     // [kp*16+d][co]
    __shared__ __align__(16) u32 lin[2784];    // [ky][58 px][16 dwords]
    __shared__ float red[256];
    int n = blockIdx.x, y = blockIdx.y, t = threadIdx.x;
    int co = t & 63, xg = t >> 6;
    const u32* qwd = (const u32*)qw;
    for (int gi = t; gi < 9216; gi += 256) lw[gi] = qwd[gi];
    const u32* qind = (const u32*)qin;
    size_t imgdw = (size_t)(1 + n * ROWS_PI) * 1024;
    for (int gi = t; gi < 2784; gi += 256) {
        int ky = gi / 928, j = gi - ky * 928;
        lin[gi] = qind[imgdw + (size_t)(y + ky) * 1024 - 16 + j];
    }
    __syncthreads();

    int acc[14];
#pragma unroll
    for (int i = 0; i < 14; i++) acc[i] = 0;
#pragma unroll 1
    for (int ch = 0; ch < 4; ch++) {
        u32 wr[36];
#pragma unroll
        for (int kp = 0; kp < 9; kp++)
#pragma unroll
            for (int dd = 0; dd < 4; dd++)
                wr[kp * 4 + dd] = lw[(kp * 16 + ch * 4 + dd) * 64 + co];
#pragma unroll
        for (int i = 0; i < 14; i++) {
            int x = xg * 14 + i;
#pragma unroll
            for (int ky = 0; ky < 3; ky++) {
#pragma unroll
                for (int kx = 0; kx < 3; kx++) {
                    const uint4 iv = *(const uint4*)&lin[ky * 928 + (x + kx) * 16 + ch * 4];
                    int kp4 = (ky * 3 + kx) * 4;
                    acc[i] = dot4i8(iv.x, wr[kp4 + 0], acc[i]);
                    acc[i] = dot4i8(iv.y, wr[kp4 + 1], acc[i]);
                    acc[i] = dot4i8(iv.z, wr[kp4 + 2], acc[i]);
                    acc[i] = dot4i8(iv.w, wr[kp4 + 3], acc[i]);
                }
            }
        }
    }
    // epilogue
    float inv = g[co] * rsqrtf(v[co] + 1e-5f);
    float sIn = SECOND ? scal[3] / 255.f : scal[0] / 127.f;
    float sW  = SECOND ? scal[2] / 127.f : scal[1] / 127.f;
    float alpha = sIn * sW * inv;
    float beta = b[co] - m[co] * inv;
    int wofs = SECOND ? (wsum[co] << 7) : 0;
    float sx = scal[0] / 127.f;
    float lmax = 0.f;
    size_t rowb = (size_t)(n * 56 + y) * 3584;
    const signed char* idrow = SECOND ? (const signed char*)(qid + (size_t)(2 + n * ROWS_PI + y) * PADROW)
                                      : (const signed char*)nullptr;
#pragma unroll
    for (int i = 0; i < 14; i++) {
        int x = xg * 14 + i;
        float o = (float)(acc[i] + wofs) * alpha + beta;
        if (SECOND) o += sx * (float)idrow[x * 64 + co];
        outp[rowb + x * 64 + co] = o;
        lmax = fmaxf(lmax, o);
    }
    red[t] = lmax; __syncthreads();
    for (int s = 128; s > 0; s >>= 1) {
        if (t < s) red[t] = fmaxf(red[t], red[t + s]);
        __syncthreads();
    }
    if (t == 0) atomicMax((u32*)rmax, __float_as_uint(red[0]));
}

// ---------------- K6: quantize conv1 output -> q1-128 padded int8 ----------------
__global__ __launch_bounds__(256) void k_quant_relu1(const float* __restrict__ of,
                                                     char* __restrict__ qpad,
                                                     const float* __restrict__ scal) {
    int n = blockIdx.x, yy = blockIdx.y, t = threadIdx.x;
    u32* row = (u32*)(qpad + (size_t)(1 + n * ROWS_PI + yy) * PADROW);
    if (n == 0 && yy == 0) {
        u32* r0 = (u32*)qpad;
        for (int j = t; j < 1024; j += 256) r0[j] = 0x80808080u;
    }
    if (yy == 0 || yy == 57) {
        for (int j = t; j < 1024; j += 256) row[j] = 0x80808080u;
        return;
    }
    int y = yy - 1;
    float s1 = scal[3] / 255.f;
    char* rowb = (char*)row;
    const float* orow = of + (size_t)(n * 56 + y) * 3584;
    for (int idx = t; idx < 3584; idx += 256) {
        float vv = fmaxf(orow[idx], 0.f);
        float q = fminf(rintf(vv / s1), 255.f);
        rowb[idx] = (char)((int)q - 128);
    }
    for (int j = 896 + t; j < 1024; j += 256) row[j] = 0x80808080u;
}

// ---------------- K8: final quantize + NHWC->NCHW transpose ----------------
__global__ __launch_bounds__(256) void k_final(const float* __restrict__ of,
                                               const float* __restrict__ scal,
                                               float* __restrict__ outp) {
    int n = blockIdx.x, y = blockIdx.y, t = threadIdx.x;
    __shared__ float lt[64 * 57];
    float s2 = scal[4] / 255.f;
    const float* orow = of + (size_t)(n * 56 + y) * 3584;
    for (int idx = t; idx < 3584; idx += 256) {
        int co = idx & 63, xx = idx >> 6;
        float vv = fmaxf(orow[idx], 0.f);
        float q = fminf(rintf(vv / s2), 255.f);
        lt[co * 57 + xx] = q * s2;
    }
    __syncthreads();
    for (int idx = t; idx < 3584; idx += 256) {
        int co = idx / 56, xx = idx - co * 56;
        outp[(size_t)n * 200704 + (size_t)co * 3136 + y * 56 + xx] = lt[co * 57 + xx];
    }
}

// ---------------- K9: combine bit-stats into HM_act / HM_energy ----------------
__global__ __launch_bounds__(512) void k_hm(const int* __restrict__ stx, const int* __restrict__ stq,
                                            const int* __restrict__ wb1, const int* __restrict__ wb2,
                                            float* __restrict__ outp) {
    int t = threadIdx.x;   // t = ci*8 + k
    long long act = 0, en = 0;
#pragma unroll
    for (int w = 0; w < 2; w++) {
        const int* st = w ? stq : stx;
        const int* wb = w ? wb2 : wb1;
        long long s[9];
#pragma unroll
        for (int j = 0; j < 9; j++) s[j] = st[j * 512 + t];
        const int* wrow = wb + t * 9;
        int w0 = wrow[0], w1_ = wrow[1], w2_ = wrow[2], w3 = wrow[3], w4 = wrow[4],
            w5 = wrow[5], w6 = wrow[6], w7 = wrow[7], w8 = wrow[8];
        long long wall = (long long)w0 + w1_ + w2_ + w3 + w4 + w5 + w6 + w7 + w8;
        long long wr0 = (long long)w0 + w1_ + w2_;       // ky=0 row
        long long wr2 = (long long)w6 + w7 + w8;         // ky=2 row
        long long wc0 = (long long)w0 + w3 + w6;         // kx=0 col
        long long wc2 = (long long)w2_ + w5 + w8;        // kx=2 col
        en += s[0] * wall - s[1] * wr2 - s[2] * wr0 - s[3] * wc2 - s[4] * wc0
            + s[5] * w8 + s[6] * w6 + s[7] * w2_ + s[8] * w0;
        act += s[0];
    }
    __shared__ long long r1[512];
    r1[t] = en; __syncthreads();
    for (int s = 256; s > 0; s >>= 1) { if (t < s) r1[t] += r1[t + s]; __syncthreads(); }
    long long etot = r1[0]; __syncthreads();
    r1[t] = act; __syncthreads();
    for (int s = 256; s > 0; s >>= 1) { if (t < s) r1[t] += r1[t + s]; __syncthreads(); }
    if (t == 0) {
        outp[OUTN]     = (float)r1[0];   // HM_act
        outp[OUTN + 1] = (float)etot;    // HM_energy
    }
}

extern "C" void kernel_launch(void* const* d_in, const int* in_sizes, int n_in,
                              void* d_out, int out_size, void* d_ws, size_t ws_size,
                              hipStream_t stream) {
    if (ws_size < WS_NEED) return;
    const float* x  = (const float*)d_in[0];
    const float* w1 = (const float*)d_in[1];
    const float* w2 = (const float*)d_in[2];
    const float* g1 = (const float*)d_in[3];
    const float* b1 = (const float*)d_in[4];
    const float* m1 = (const float*)d_in[5];
    const float* v1 = (const float*)d_in[6];
    const float* g2 = (const float*)d_in[7];
    const float* b2 = (const float*)d_in[8];
    const float* m2 = (const float*)d_in[9];
    const float* v2 = (const float*)d_in[10];
    char* ws = (char*)d_ws;
    float* scal = (float*)ws;
    char* qx = ws + OFS_QX;
    char* q1 = ws + OFS_Q1;
    float* o1 = (float*)(ws + OFS_O1);
    float* o2 = (float*)(ws + OFS_O2);
    char* qw1 = ws + OFS_QW1;
    char* qw2 = ws + OFS_QW2;
    int* wb1 = (int*)(ws + OFS_WB1);
    int* wb2 = (int*)(ws + OFS_WB2);
    int* wsum = (int*)(ws + OFS_WSUM);
    int* stx = (int*)(ws + OFS_STX);
    int* stq = (int*)(ws + OFS_STQ);
    float* outp = (float*)d_out;

    k_init<<<18, 256, 0, stream>>>(scal, stx, stq);
    k_absmax<<<dim3(1024, 3), 256, 0, stream>>>(x, w1, w2, scal);
    k_quant_x<<<dim3(16, 58), 256, 0, stream>>>(x, qx, scal);
    k_quant_w<<<2, dim3(64, 9), 0, stream>>>(w1, w2, qw1, qw2, wb1, wb2, wsum, scal);
    k_stats<<<dim3(16, 14), 256, 0, stream>>>(qx, 0u, stx);
    k_conv<0><<<dim3(16, 56), 256, 0, stream>>>(qx, qw1, nullptr, nullptr,
                                                g1, b1, m1, v1, scal, o1, scal + 3);
    k_quant_relu1<<<dim3(16, 58), 256, 0, stream>>>(o1, q1, scal);
    k_stats<<<dim3(16, 14), 256, 0, stream>>>(q1, 0x80u, stq);
    k_conv<1><<<dim3(16, 56), 256, 0, stream>>>(q1, qw2, wsum, qx,
                                                g2, b2, m2, v2, scal, o2, scal + 4);
    k_final<<<dim3(16, 56), 256, 0, stream>>>(o2, scal, outp);
    k_hm<<<1, 512, 0, stream>>>(stx, stq, wb1, wb2, outp);
}

// Round 3
// 248.632 us; speedup vs baseline: 1.6847x; 1.0920x over previous
//
#include <hip/hip_runtime.h>

using u32 = unsigned int;
typedef int v4i __attribute__((ext_vector_type(4)));

// ---------------- workspace layout (bytes) ----------------
constexpr int  N_IMG   = 16;
constexpr int  PADROW  = 4096;          // 64 cols * 64 ch bytes
constexpr int  ROWS_PI = 58;            // 56 real + top/bottom pad rows
constexpr size_t OFS_QX  = 4096;
constexpr size_t SZ_QPAD = (size_t)(1 + N_IMG * ROWS_PI) * PADROW;   // 3,805,184
constexpr size_t OFS_Q1  = OFS_QX + SZ_QPAD;
constexpr size_t OFS_O1  = OFS_Q1 + SZ_QPAD;
constexpr size_t SZ_OF   = (size_t)N_IMG * 56 * 56 * 64 * 4;         // 12,845,056
constexpr size_t OFS_O2  = OFS_O1 + SZ_OF;
constexpr size_t OFS_QW1 = OFS_O2 + SZ_OF;
constexpr size_t OFS_QW2 = OFS_QW1 + 36864;
constexpr size_t OFS_WB1 = OFS_QW2 + 36864;
constexpr size_t OFS_WB2 = OFS_WB1 + 18432;
constexpr size_t OFS_WSUM= OFS_WB2 + 18432;
constexpr size_t OFS_STX = OFS_WSUM + 256;      // 4608 ints (aggregated over images)
constexpr size_t OFS_STQ = OFS_STX + 294912;
constexpr size_t WS_NEED = OFS_STQ + 294912;
constexpr size_t OUTN    = (size_t)16 * 64 * 56 * 56;                // 3,211,264

// ---------------- K0: zero scalars + aggregated stats ----------------
__global__ __launch_bounds__(256) void k_init(float* scal, int* gstx, int* gstq) {
    int i = blockIdx.x * 256 + threadIdx.x;
    if (i < 8) scal[i] = 0.f;
    if (i < 4608) { gstx[i] = 0; gstq[i] = 0; }
}

// ---------------- K1: absmax of x / w1 / w2 ----------------
__global__ __launch_bounds__(256) void k_absmax(const float* __restrict__ x,
                                                const float* __restrict__ w1,
                                                const float* __restrict__ w2,
                                                float* __restrict__ scal) {
    const float* p; int n; int slot;
    if (blockIdx.y == 0)      { p = x;  n = 16*64*56*56; slot = 0; }
    else if (blockIdx.y == 1) { p = w1; n = 64*64*9;     slot = 1; }
    else                      { p = w2; n = 64*64*9;     slot = 2; }
    float m = 0.f;
    for (int i = blockIdx.x * 256 + threadIdx.x; i < n; i += gridDim.x * 256)
        m = fmaxf(m, fabsf(p[i]));
    __shared__ float red[256];
    red[threadIdx.x] = m; __syncthreads();
    for (int s = 128; s > 0; s >>= 1) {
        if (threadIdx.x < s) red[threadIdx.x] = fmaxf(red[threadIdx.x], red[threadIdx.x + s]);
        __syncthreads();
    }
    if (threadIdx.x == 0) atomicMax((u32*)(scal + slot), __float_as_uint(red[0]));
}

// ---------------- K2: quantize x -> padded NHWC int8 ----------------
__global__ __launch_bounds__(256) void k_quant_x(const float* __restrict__ x,
                                                 char* __restrict__ qpad,
                                                 const float* __restrict__ scal) {
    int n = blockIdx.x, yy = blockIdx.y, t = threadIdx.x;
    u32* row = (u32*)(qpad + (size_t)(1 + n * ROWS_PI + yy) * PADROW);
    if (n == 0 && yy == 0) {                  // global leading zero row
        u32* r0 = (u32*)qpad;
        for (int j = t; j < 1024; j += 256) r0[j] = 0u;
    }
    if (yy == 0 || yy == 57) {                // per-image pad rows
        for (int j = t; j < 1024; j += 256) row[j] = 0u;
        return;
    }
    int y = yy - 1;
    float sx = scal[0] / 127.f;
    __shared__ char lq[4096];
    for (int idx = t; idx < 3584; idx += 256) {
        int c = idx / 56, xx = idx - c * 56;
        float v = x[(size_t)n * 200704 + (size_t)c * 3136 + y * 56 + xx];
        float q = rintf(v / sx);
        q = fminf(fmaxf(q, -127.f), 127.f);
        lq[xx * 64 + c] = (char)(int)q;
    }
    __syncthreads();
    u32* lqd = (u32*)lq;
    for (int j = t; j < 1024; j += 256) row[j] = (j < 896) ? lqd[j] : 0u;
}

// ---------------- K2b: quantize weights -> [tap][co][ci], WB bit-stats, wsum ----------------
__global__ void k_quant_w(const float* __restrict__ w1, const float* __restrict__ w2,
                          char* __restrict__ qw1, char* __restrict__ qw2,
                          int* __restrict__ wb1, int* __restrict__ wb2,
                          int* __restrict__ wsum, const float* __restrict__ scal) {
    int wsel = blockIdx.x;
    const float* w = wsel ? w2 : w1;
    char* qw = wsel ? qw2 : qw1;
    int* wb  = wsel ? wb2 : wb1;
    float s = scal[1 + wsel] / 127.f;
    int ci = threadIdx.x, kp = threadIdx.y;
    int bc[8] = {0,0,0,0,0,0,0,0};
    for (int co = 0; co < 64; co++) {
        float v = w[((size_t)co * 64 + ci) * 9 + kp];
        float qf = rintf(v / s);
        qf = fminf(fmaxf(qf, -127.f), 127.f);
        int q = (int)qf;
        qw[(kp * 64 + co) * 64 + ci] = (char)q;
        u32 u = (u32)q & 0xFFu;
#pragma unroll
        for (int k = 0; k < 8; k++) bc[k] += (u >> k) & 1;
    }
#pragma unroll
    for (int k = 0; k < 8; k++) wb[(ci * 8 + k) * 9 + kp] = bc[k];
    __syncthreads();
    if (wsel == 1) {
        int tid = threadIdx.y * 64 + threadIdx.x;
        if (tid < 64) {    // wsum[co] = sum of all 576 int8 weights of output channel co
            const u32* q = (const u32*)qw2;
            int ssum = 0;
            for (int kp2 = 0; kp2 < 9; kp2++)
                for (int c4 = 0; c4 < 16; c4++) {
                    u32 v = q[(kp2 * 64 + tid) * 16 + c4];
                    ssum += (int)(signed char)(v & 0xFF) + (int)(signed char)((v >> 8) & 0xFF)
                          + (int)(signed char)((v >> 16) & 0xFF) + (int)(signed char)(v >> 24);
                }
            wsum[tid] = ssum;
        }
    }
}

// ---------------- K3: bit stats via packed counters, no LDS atomics ----------------
// gst layout: j*512 + ci*8 + k ; j: 0=T 1=Rtop 2=Rbot 3=Cleft 4=Cright 5=(0,0) 6=(0,55) 7=(55,0) 8=(55,55)
static __device__ __forceinline__ void unpack_acc(u32 v, u32 pk[8]) {
#pragma unroll
    for (int k = 0; k < 8; k++) pk[k] += (v >> k) & 0x01010101u;
}

static __device__ __forceinline__ void reduce_cat(u32* red, int* gdst, const u32 pk[8],
                                                  bool active, int t) {
#pragma unroll
    for (int k = 0; k < 8; k++) red[k * 256 + t] = active ? pk[k] : 0u;
    __syncthreads();
#pragma unroll
    for (int p = t; p < 512; p += 256) {
        int ci = p >> 3, k = p & 7, ci4 = ci >> 2, b = ci & 3;
        int sum = 0;
#pragma unroll
        for (int xo = 0; xo < 16; xo++)
            sum += (red[k * 256 + xo * 16 + ci4] >> (8 * b)) & 0xFF;
        if (sum) atomicAdd(&gdst[p], sum);
    }
    __syncthreads();
}

__global__ __launch_bounds__(256) void k_stats(const char* __restrict__ qpad, u32 xorm,
                                               int* __restrict__ gst) {
    int n = blockIdx.x, slab = blockIdx.y, t = threadIdx.x;
    int ci4 = t & 15, xo = t >> 4;
    const u32* img = (const u32*)(qpad + (size_t)(2 + n * ROWS_PI) * PADROW); // real row 0
    u32 xm = xorm * 0x01010101u;
    __shared__ u32 red[2048];
    int y0 = slab * 4;

    {   // main total (j=0)
        u32 pk[8] = {0,0,0,0,0,0,0,0};
#pragma unroll
        for (int r = 0; r < 4; r++) {
            const u32* row = img + (size_t)(y0 + r) * 1024;
#pragma unroll
            for (int j = 0; j < 4; j++) {
                int xx = xo + 16 * j;
                if (xx < 56) unpack_acc(row[xx * 16 + ci4] ^ xm, pk);
            }
        }
        reduce_cat(red, gst + 0 * 512, pk, true, t);
    }
    {   // Cleft (j=3)
        u32 pk[8] = {0,0,0,0,0,0,0,0};
        bool act = (xo == 0);
        if (act)
#pragma unroll
            for (int r = 0; r < 4; r++)
                unpack_acc(img[(size_t)(y0 + r) * 1024 + ci4] ^ xm, pk);
        reduce_cat(red, gst + 3 * 512, pk, act, t);
    }
    {   // Cright (j=4)
        u32 pk[8] = {0,0,0,0,0,0,0,0};
        bool act = (xo == 7);
        if (act)
#pragma unroll
            for (int r = 0; r < 4; r++)
                unpack_acc(img[(size_t)(y0 + r) * 1024 + 55 * 16 + ci4] ^ xm, pk);
        reduce_cat(red, gst + 4 * 512, pk, act, t);
    }
    if (slab == 0) {   // Rtop (j=1) + corners 5,6
        u32 pk[8] = {0,0,0,0,0,0,0,0};
#pragma unroll
        for (int j = 0; j < 4; j++) {
            int xx = xo + 16 * j;
            if (xx < 56) unpack_acc(img[xx * 16 + ci4] ^ xm, pk);
        }
        reduce_cat(red, gst + 1 * 512, pk, true, t);
        if (t < 32) {
            int which = t >> 4, c4 = t & 15;
            u32 v = img[(which ? 55 : 0) * 16 + c4] ^ xm;
            for (int b = 0; b < 4; b++)
                for (int k = 0; k < 8; k++)
                    if ((v >> (8 * b + k)) & 1)
                        atomicAdd(&gst[(5 + which) * 512 + (c4 * 4 + b) * 8 + k], 1);
        }
    }
    if (slab == 13) {  // Rbot (j=2) + corners 7,8
        u32 pk[8] = {0,0,0,0,0,0,0,0};
#pragma unroll
        for (int j = 0; j < 4; j++) {
            int xx = xo + 16 * j;
            if (xx < 56) unpack_acc(img[(size_t)55 * 1024 + xx * 16 + ci4] ^ xm, pk);
        }
        reduce_cat(red, gst + 2 * 512, pk, true, t);
        if (t < 32) {
            int which = t >> 4, c4 = t & 15;
            u32 v = img[(size_t)55 * 1024 + (which ? 55 : 0) * 16 + c4] ^ xm;
            for (int b = 0; b < 4; b++)
                for (int k = 0; k < 8; k++)
                    if ((v >> (8 * b + k)) & 1)
                        atomicAdd(&gst[(7 + which) * 512 + (c4 * 4 + b) * 8 + k], 1);
        }
    }
}

// ---------------- K5/K7: int8 conv 3x3 via MFMA implicit GEMM ----------------
// M = x (56, padded to 64 = 4 tiles), N = co (64 = 4 tiles), K = 576 (9 taps x 64 ci).
// A-frag: lane holds A[m=lane&15][k-bytes quad*16..+15] = contiguous ci at one tap.
// B-frag: lane holds B[k-bytes quad*16..+15][n=lane&15]; lb layout [tap][co][ci] pitch 80B.
// C/D: row(m=x)=quad*4+reg, col(n=co)=lane&15  [HW-verified mapping].
template <int SECOND>
__global__ __launch_bounds__(256, 2) void k_conv(const char* __restrict__ qin,
                                              const char* __restrict__ qw,
                                              const int* __restrict__ wsum,
                                              const char* __restrict__ qid,
                                              const float* __restrict__ g, const float* __restrict__ b,
                                              const float* __restrict__ m_, const float* __restrict__ v,
                                              const float* __restrict__ scal,
                                              float* __restrict__ outp, float* __restrict__ rmax) {
    __shared__ __align__(16) u32 lb[11520];    // B: 576 rows (tap,co) x 20 dw (64B data + 16B pad)
    __shared__ __align__(16) u32 lin[3960];    // input: 3 rows x 66 px x 20 dw
    __shared__ float red[256];
    int n = blockIdx.x, y = blockIdx.y, t = threadIdx.x;
    int w = t >> 6, lane = t & 63, mm = lane & 15, quad = lane >> 4;

    const uint4* bq4 = (const uint4*)qw;                 // 2304 uint4
    for (int j4 = t; j4 < 2304; j4 += 256) {
        int row = j4 >> 2, rem = j4 & 3;
        *(uint4*)&lb[row * 20 + rem * 4] = bq4[j4];
    }
    const uint4* qin4 = (const uint4*)qin;
    for (int g4 = t; g4 < 792; g4 += 256) {              // 3 rows x 264 uint4 (px -1..64)
        int ky = g4 / 264, r = g4 - ky * 264;
        int px = r >> 2, rem = r & 3;
        *(uint4*)&lin[(ky * 66 + px) * 20 + rem * 4] =
            qin4[(size_t)(1 + n * ROWS_PI + y + ky) * 256 - 4 + r];
    }
    __syncthreads();

    v4i acc[4] = {{0,0,0,0},{0,0,0,0},{0,0,0,0},{0,0,0,0}};
#pragma unroll
    for (int ky = 0; ky < 3; ky++) {
#pragma unroll
        for (int kx = 0; kx < 3; kx++) {
            int px = w * 16 + mm + kx;                   // lin idx = (x+kx-1)+1
            v4i a = *(const v4i*)&lin[(ky * 66 + px) * 20 + quad * 4];
            int tap = ky * 3 + kx;
#pragma unroll
            for (int nt = 0; nt < 4; nt++) {
                int co = nt * 16 + mm;
                v4i bf = *(const v4i*)&lb[(tap * 64 + co) * 20 + quad * 4];
                acc[nt] = __builtin_amdgcn_mfma_i32_16x16x64_i8(a, bf, acc[nt], 0, 0, 0);
            }
        }
    }
    // epilogue
    float sIn = SECOND ? scal[3] / 255.f : scal[0] / 127.f;
    float sW  = SECOND ? scal[2] / 127.f : scal[1] / 127.f;
    float sx = scal[0] / 127.f;
    float lmax = 0.f;
    size_t rowb = (size_t)(n * 56 + y) * 3584;
    const signed char* idrow = SECOND ? (const signed char*)(qid + (size_t)(2 + n * ROWS_PI + y) * PADROW)
                                      : (const signed char*)nullptr;
#pragma unroll
    for (int nt = 0; nt < 4; nt++) {
        int co = nt * 16 + mm;
        float inv = g[co] * rsqrtf(v[co] + 1e-5f);
        float alpha = sIn * sW * inv;
        float beta = b[co] - m_[co] * inv;
        int wofs = SECOND ? (wsum[co] << 7) : 0;
#pragma unroll
        for (int r = 0; r < 4; r++) {
            int x = w * 16 + quad * 4 + r;
            if (x < 56) {
                float o = (float)(acc[nt][r] + wofs) * alpha + beta;
                if (SECOND) o += sx * (float)idrow[x * 64 + co];
                outp[rowb + x * 64 + co] = o;
                lmax = fmaxf(lmax, o);
            }
        }
    }
    red[t] = lmax; __syncthreads();
    for (int s = 128; s > 0; s >>= 1) {
        if (t < s) red[t] = fmaxf(red[t], red[t + s]);
        __syncthreads();
    }
    if (t == 0) atomicMax((u32*)rmax, __float_as_uint(red[0]));
}

// ---------------- K6: quantize conv1 output -> q1-128 padded int8 ----------------
__global__ __launch_bounds__(256) void k_quant_relu1(const float* __restrict__ of,
                                                     char* __restrict__ qpad,
                                                     const float* __restrict__ scal) {
    int n = blockIdx.x, yy = blockIdx.y, t = threadIdx.x;
    u32* row = (u32*)(qpad + (size_t)(1 + n * ROWS_PI + yy) * PADROW);
    if (n == 0 && yy == 0) {
        u32* r0 = (u32*)qpad;
        for (int j = t; j < 1024; j += 256) r0[j] = 0x80808080u;
    }
    if (yy == 0 || yy == 57) {
        for (int j = t; j < 1024; j += 256) row[j] = 0x80808080u;
        return;
    }
    int y = yy - 1;
    float s1 = scal[3] / 255.f;
    char* rowb = (char*)row;
    const float* orow = of + (size_t)(n * 56 + y) * 3584;
    for (int idx = t; idx < 3584; idx += 256) {
        float vv = fmaxf(orow[idx], 0.f);
        float q = fminf(rintf(vv / s1), 255.f);
        rowb[idx] = (char)((int)q - 128);
    }
    for (int j = 896 + t; j < 1024; j += 256) row[j] = 0x80808080u;
}

// ---------------- K8: final quantize + NHWC->NCHW transpose ----------------
__global__ __launch_bounds__(256) void k_final(const float* __restrict__ of,
                                               const float* __restrict__ scal,
                                               float* __restrict__ outp) {
    int n = blockIdx.x, y = blockIdx.y, t = threadIdx.x;
    __shared__ float lt[64 * 57];
    float s2 = scal[4] / 255.f;
    const float* orow = of + (size_t)(n * 56 + y) * 3584;
    for (int idx = t; idx < 3584; idx += 256) {
        int co = idx & 63, xx = idx >> 6;
        float vv = fmaxf(orow[idx], 0.f);
        float q = fminf(rintf(vv / s2), 255.f);
        lt[co * 57 + xx] = q * s2;
    }
    __syncthreads();
    for (int idx = t; idx < 3584; idx += 256) {
        int co = idx / 56, xx = idx - co * 56;
        outp[(size_t)n * 200704 + (size_t)co * 3136 + y * 56 + xx] = lt[co * 57 + xx];
    }
}

// ---------------- K9: combine bit-stats into HM_act / HM_energy ----------------
__global__ __launch_bounds__(512) void k_hm(const int* __restrict__ stx, const int* __restrict__ stq,
                                            const int* __restrict__ wb1, const int* __restrict__ wb2,
                                            float* __restrict__ outp) {
    int t = threadIdx.x;   // t = ci*8 + k
    long long act = 0, en = 0;
#pragma unroll
    for (int w = 0; w < 2; w++) {
        const int* st = w ? stq : stx;
        const int* wb = w ? wb2 : wb1;
        long long s[9];
#pragma unroll
        for (int j = 0; j < 9; j++) s[j] = st[j * 512 + t];
        const int* wrow = wb + t * 9;
        int w0 = wrow[0], w1_ = wrow[1], w2_ = wrow[2], w3 = wrow[3], w4 = wrow[4],
            w5 = wrow[5], w6 = wrow[6], w7 = wrow[7], w8 = wrow[8];
        long long wall = (long long)w0 + w1_ + w2_ + w3 + w4 + w5 + w6 + w7 + w8;
        long long wr0 = (long long)w0 + w1_ + w2_;
        long long wr2 = (long long)w6 + w7 + w8;
        long long wc0 = (long long)w0 + w3 + w6;
        long long wc2 = (long long)w2_ + w5 + w8;
        en += s[0] * wall - s[1] * wr2 - s[2] * wr0 - s[3] * wc2 - s[4] * wc0
            + s[5] * w8 + s[6] * w6 + s[7] * w2_ + s[8] * w0;
        act += s[0];
    }
    __shared__ long long r1[512];
    r1[t] = en; __syncthreads();
    for (int s = 256; s > 0; s >>= 1) { if (t < s) r1[t] += r1[t + s]; __syncthreads(); }
    long long etot = r1[0]; __syncthreads();
    r1[t] = act; __syncthreads();
    for (int s = 256; s > 0; s >>= 1) { if (t < s) r1[t] += r1[t + s]; __syncthreads(); }
    if (t == 0) {
        outp[OUTN]     = (float)r1[0];   // HM_act
        outp[OUTN + 1] = (float)etot;    // HM_energy
    }
}

extern "C" void kernel_launch(void* const* d_in, const int* in_sizes, int n_in,
                              void* d_out, int out_size, void* d_ws, size_t ws_size,
                              hipStream_t stream) {
    if (ws_size < WS_NEED) return;
    const float* x  = (const float*)d_in[0];
    const float* w1 = (const float*)d_in[1];
    const float* w2 = (const float*)d_in[2];
    const float* g1 = (const float*)d_in[3];
    const float* b1 = (const float*)d_in[4];
    const float* m1 = (const float*)d_in[5];
    const float* v1 = (const float*)d_in[6];
    const float* g2 = (const float*)d_in[7];
    const float* b2 = (const float*)d_in[8];
    const float* m2 = (const float*)d_in[9];
    const float* v2 = (const float*)d_in[10];
    char* ws = (char*)d_ws;
    float* scal = (float*)ws;
    char* qx = ws + OFS_QX;
    char* q1 = ws + OFS_Q1;
    float* o1 = (float*)(ws + OFS_O1);
    float* o2 = (float*)(ws + OFS_O2);
    char* qw1 = ws + OFS_QW1;
    char* qw2 = ws + OFS_QW2;
    int* wb1 = (int*)(ws + OFS_WB1);
    int* wb2 = (int*)(ws + OFS_WB2);
    int* wsum = (int*)(ws + OFS_WSUM);
    int* stx = (int*)(ws + OFS_STX);
    int* stq = (int*)(ws + OFS_STQ);
    float* outp = (float*)d_out;

    k_init<<<18, 256, 0, stream>>>(scal, stx, stq);
    k_absmax<<<dim3(1024, 3), 256, 0, stream>>>(x, w1, w2, scal);
    k_quant_x<<<dim3(16, 58), 256, 0, stream>>>(x, qx, scal);
    k_quant_w<<<2, dim3(64, 9), 0, stream>>>(w1, w2, qw1, qw2, wb1, wb2, wsum, scal);
    k_stats<<<dim3(16, 14), 256, 0, stream>>>(qx, 0u, stx);
    k_conv<0><<<dim3(16, 56), 256, 0, stream>>>(qx, qw1, nullptr, nullptr,
                                                g1, b1, m1, v1, scal, o1, scal + 3);
    k_quant_relu1<<<dim3(16, 58), 256, 0, stream>>>(o1, q1, scal);
    k_stats<<<dim3(16, 14), 256, 0, stream>>>(q1, 0x80u, stq);
    k_conv<1><<<dim3(16, 56), 256, 0, stream>>>(q1, qw2, wsum, qx,
                                                g2, b2, m2, v2, scal, o2, scal + 4);
    k_final<<<dim3(16, 56), 256, 0, stream>>>(o2, scal, outp);
    k_hm<<<1, 512, 0, stream>>>(stx, stq, wb1, wb2, outp);
}

// Round 4
// 239.568 us; speedup vs baseline: 1.7484x; 1.0378x over previous
//
#include <hip/hip_runtime.h>

using u32 = unsigned int;
typedef int v4i __attribute__((ext_vector_type(4)));

// ---------------- workspace layout (bytes) ----------------
constexpr int  N_IMG   = 16;
constexpr int  PADROW  = 4096;          // 64 cols * 64 ch bytes
constexpr int  ROWS_PI = 58;            // 56 real + top/bottom pad rows
constexpr size_t OFS_QX  = 4096;
constexpr size_t SZ_QPAD = (size_t)(1 + N_IMG * ROWS_PI) * PADROW;   // 3,805,184
constexpr size_t OFS_Q1  = OFS_QX + SZ_QPAD;
constexpr size_t OFS_O1  = OFS_Q1 + SZ_QPAD;
constexpr size_t SZ_OF   = (size_t)N_IMG * 56 * 56 * 64 * 4;         // 12,845,056
constexpr size_t OFS_O2  = OFS_O1 + SZ_OF;
constexpr size_t OFS_QW1 = OFS_O2 + SZ_OF;
constexpr size_t OFS_QW2 = OFS_QW1 + 36864;
constexpr size_t OFS_WB1 = OFS_QW2 + 36864;
constexpr size_t OFS_WB2 = OFS_WB1 + 18432;
constexpr size_t OFS_WSUM= OFS_WB2 + 18432;
constexpr size_t OFS_STX = OFS_WSUM + 256;      // 4608 ints (aggregated over images)
constexpr size_t OFS_STQ = OFS_STX + 294912;
constexpr size_t WS_NEED = OFS_STQ + 294912;
constexpr size_t OUTN    = (size_t)16 * 64 * 56 * 56;                // 3,211,264

// ---------------- K0: zero scalars + aggregated stats + wsum ----------------
__global__ __launch_bounds__(256) void k_init(float* scal, int* gstx, int* gstq, int* wsum) {
    int i = blockIdx.x * 256 + threadIdx.x;
    if (i < 8) scal[i] = 0.f;
    if (i < 64) wsum[i] = 0;
    if (i < 4608) { gstx[i] = 0; gstq[i] = 0; }
}

// ---------------- K1: absmax of x / w1 / w2 ----------------
__global__ __launch_bounds__(256) void k_absmax(const float* __restrict__ x,
                                                const float* __restrict__ w1,
                                                const float* __restrict__ w2,
                                                float* __restrict__ scal) {
    const float* p; int n; int slot;
    if (blockIdx.y == 0)      { p = x;  n = 16*64*56*56; slot = 0; }
    else if (blockIdx.y == 1) { p = w1; n = 64*64*9;     slot = 1; }
    else                      { p = w2; n = 64*64*9;     slot = 2; }
    float m = 0.f;
    for (int i = blockIdx.x * 256 + threadIdx.x; i < n; i += gridDim.x * 256)
        m = fmaxf(m, fabsf(p[i]));
    __shared__ float red[256];
    red[threadIdx.x] = m; __syncthreads();
    for (int s = 128; s > 0; s >>= 1) {
        if (threadIdx.x < s) red[threadIdx.x] = fmaxf(red[threadIdx.x], red[threadIdx.x + s]);
        __syncthreads();
    }
    if (threadIdx.x == 0) atomicMax((u32*)(scal + slot), __float_as_uint(red[0]));
}

// ---------------- K2: quantize x -> padded NHWC int8 ----------------
__global__ __launch_bounds__(256) void k_quant_x(const float* __restrict__ x,
                                                 char* __restrict__ qpad,
                                                 const float* __restrict__ scal) {
    int n = blockIdx.x, yy = blockIdx.y, t = threadIdx.x;
    u32* row = (u32*)(qpad + (size_t)(1 + n * ROWS_PI + yy) * PADROW);
    if (n == 0 && yy == 0) {                  // global leading zero row
        u32* r0 = (u32*)qpad;
        for (int j = t; j < 1024; j += 256) r0[j] = 0u;
    }
    if (yy == 0 || yy == 57) {                // per-image pad rows
        for (int j = t; j < 1024; j += 256) row[j] = 0u;
        return;
    }
    int y = yy - 1;
    float sx = scal[0] / 127.f;
    __shared__ char lq[4096];
    for (int idx = t; idx < 3584; idx += 256) {
        int c = idx / 56, xx = idx - c * 56;
        float v = x[(size_t)n * 200704 + (size_t)c * 3136 + y * 56 + xx];
        float q = rintf(v / sx);
        q = fminf(fmaxf(q, -127.f), 127.f);
        lq[xx * 64 + c] = (char)(int)q;
    }
    __syncthreads();
    u32* lqd = (u32*)lq;
    for (int j = t; j < 1024; j += 256) row[j] = (j < 896) ? lqd[j] : 0u;
}

// ---------------- K2b: quantize weights -> [tap][co][ci], WB bit-stats, wsum ----------------
// grid (2 wsel, 9 kp) x 256 threads; t = cg*64 + co (wave = all 64 co for fixed cg).
// Each thread quantizes 16 ci values -> one uint4 store; bit-stats via ballot+popcount.
__global__ __launch_bounds__(256) void k_quant_w(const float* __restrict__ w1,
                                                 const float* __restrict__ w2,
                                                 char* __restrict__ qw1, char* __restrict__ qw2,
                                                 int* __restrict__ wb1, int* __restrict__ wb2,
                                                 int* __restrict__ wsum,
                                                 const float* __restrict__ scal) {
    int wsel = blockIdx.x, kp = blockIdx.y;
    const float* w = wsel ? w2 : w1;
    char* qw = wsel ? qw2 : qw1;
    int* wb  = wsel ? wb2 : wb1;
    float s = scal[1 + wsel] / 127.f;
    int t = threadIdx.x, co = t & 63, cg = t >> 6;
    int ci0 = cg * 16;
    signed char qv[16];
    int qsum = 0;
#pragma unroll
    for (int i = 0; i < 16; i++) {
        int ci = ci0 + i;
        float v = w[((size_t)co * 64 + ci) * 9 + kp];
        float qf = rintf(v / s);
        qf = fminf(fmaxf(qf, -127.f), 127.f);
        int q = (int)qf;
        qv[i] = (signed char)q;
        qsum += q;
    }
    u32 pk[4];
#pragma unroll
    for (int d = 0; d < 4; d++)
        pk[d] = ((u32)(unsigned char)qv[d*4]) | ((u32)(unsigned char)qv[d*4+1] << 8)
              | ((u32)(unsigned char)qv[d*4+2] << 16) | ((u32)(unsigned char)qv[d*4+3] << 24);
    *(uint4*)&qw[(size_t)(kp * 64 + co) * 64 + ci0] = *(uint4*)pk;
    // bit-stats: for each (ci,k), count over all 64 co via wave ballot
#pragma unroll
    for (int i = 0; i < 16; i++) {
        u32 u = (u32)(unsigned char)qv[i];
#pragma unroll
        for (int k = 0; k < 8; k++) {
            unsigned long long bal = __ballot((u >> k) & 1);
            if (co == 0) wb[((ci0 + i) * 8 + k) * 9 + kp] = __popcll(bal);
        }
    }
    // wsum[co] = sum over ci,kp (only needed for w2)
    if (wsel == 1) {
        __shared__ int wsl[256];
        wsl[t] = qsum; __syncthreads();
        if (t < 64) {
            int sum = wsl[t] + wsl[t + 64] + wsl[t + 128] + wsl[t + 192];
            atomicAdd(&wsum[t], sum);
        }
    }
}

// ---------------- K3: bit stats via packed counters, no LDS atomics ----------------
// gst layout: j*512 + ci*8 + k ; j: 0=T 1=Rtop 2=Rbot 3=Cleft 4=Cright 5=(0,0) 6=(0,55) 7=(55,0) 8=(55,55)
static __device__ __forceinline__ void unpack_acc(u32 v, u32 pk[8]) {
#pragma unroll
    for (int k = 0; k < 8; k++) pk[k] += (v >> k) & 0x01010101u;
}

static __device__ __forceinline__ void reduce_cat(u32* red, int* gdst, const u32 pk[8],
                                                  bool active, int t) {
#pragma unroll
    for (int k = 0; k < 8; k++) red[k * 256 + t] = active ? pk[k] : 0u;
    __syncthreads();
#pragma unroll
    for (int p = t; p < 512; p += 256) {
        int ci = p >> 3, k = p & 7, ci4 = ci >> 2, b = ci & 3;
        int sum = 0;
#pragma unroll
        for (int xo = 0; xo < 16; xo++)
            sum += (red[k * 256 + xo * 16 + ci4] >> (8 * b)) & 0xFF;
        if (sum) atomicAdd(&gdst[p], sum);
    }
    __syncthreads();
}

__global__ __launch_bounds__(256) void k_stats(const char* __restrict__ qpad, u32 xorm,
                                               int* __restrict__ gst) {
    int n = blockIdx.x, slab = blockIdx.y, t = threadIdx.x;
    int ci4 = t & 15, xo = t >> 4;
    const u32* img = (const u32*)(qpad + (size_t)(2 + n * ROWS_PI) * PADROW); // real row 0
    u32 xm = xorm * 0x01010101u;
    __shared__ u32 red[2048];
    int y0 = slab * 4;

    {   // main total (j=0)
        u32 pk[8] = {0,0,0,0,0,0,0,0};
#pragma unroll
        for (int r = 0; r < 4; r++) {
            const u32* row = img + (size_t)(y0 + r) * 1024;
#pragma unroll
            for (int j = 0; j < 4; j++) {
                int xx = xo + 16 * j;
                if (xx < 56) unpack_acc(row[xx * 16 + ci4] ^ xm, pk);
            }
        }
        reduce_cat(red, gst + 0 * 512, pk, true, t);
    }
    {   // Cleft (j=3)
        u32 pk[8] = {0,0,0,0,0,0,0,0};
        bool act = (xo == 0);
        if (act)
#pragma unroll
            for (int r = 0; r < 4; r++)
                unpack_acc(img[(size_t)(y0 + r) * 1024 + ci4] ^ xm, pk);
        reduce_cat(red, gst + 3 * 512, pk, act, t);
    }
    {   // Cright (j=4)
        u32 pk[8] = {0,0,0,0,0,0,0,0};
        bool act = (xo == 7);
        if (act)
#pragma unroll
            for (int r = 0; r < 4; r++)
                unpack_acc(img[(size_t)(y0 + r) * 1024 + 55 * 16 + ci4] ^ xm, pk);
        reduce_cat(red, gst + 4 * 512, pk, act, t);
    }
    if (slab == 0) {   // Rtop (j=1) + corners 5,6
        u32 pk[8] = {0,0,0,0,0,0,0,0};
#pragma unroll
        for (int j = 0; j < 4; j++) {
            int xx = xo + 16 * j;
            if (xx < 56) unpack_acc(img[xx * 16 + ci4] ^ xm, pk);
        }
        reduce_cat(red, gst + 1 * 512, pk, true, t);
        if (t < 32) {
            int which = t >> 4, c4 = t & 15;
            u32 v = img[(which ? 55 : 0) * 16 + c4] ^ xm;
            for (int b = 0; b < 4; b++)
                for (int k = 0; k < 8; k++)
                    if ((v >> (8 * b + k)) & 1)
                        atomicAdd(&gst[(5 + which) * 512 + (c4 * 4 + b) * 8 + k], 1);
        }
    }
    if (slab == 13) {  // Rbot (j=2) + corners 7,8
        u32 pk[8] = {0,0,0,0,0,0,0,0};
#pragma unroll
        for (int j = 0; j < 4; j++) {
            int xx = xo + 16 * j;
            if (xx < 56) unpack_acc(img[(size_t)55 * 1024 + xx * 16 + ci4] ^ xm, pk);
        }
        reduce_cat(red, gst + 2 * 512, pk, true, t);
        if (t < 32) {
            int which = t >> 4, c4 = t & 15;
            u32 v = img[(size_t)55 * 1024 + (which ? 55 : 0) * 16 + c4] ^ xm;
            for (int b = 0; b < 4; b++)
                for (int k = 0; k < 8; k++)
                    if ((v >> (8 * b + k)) & 1)
                        atomicAdd(&gst[(7 + which) * 512 + (c4 * 4 + b) * 8 + k], 1);
        }
    }
}

// ---------------- K5/K7: int8 conv 3x3 via MFMA implicit GEMM ----------------
template <int SECOND>
__global__ __launch_bounds__(256, 2) void k_conv(const char* __restrict__ qin,
                                              const char* __restrict__ qw,
                                              const int* __restrict__ wsum,
                                              const char* __restrict__ qid,
                                              const float* __restrict__ g, const float* __restrict__ b,
                                              const float* __restrict__ m_, const float* __restrict__ v,
                                              const float* __restrict__ scal,
                                              float* __restrict__ outp, float* __restrict__ rmax) {
    __shared__ __align__(16) u32 lb[11520];    // B: 576 rows (tap,co) x 20 dw (64B data + 16B pad)
    __shared__ __align__(16) u32 lin[3960];    // input: 3 rows x 66 px x 20 dw
    __shared__ float red[256];
    int n = blockIdx.x, y = blockIdx.y, t = threadIdx.x;
    int w = t >> 6, lane = t & 63, mm = lane & 15, quad = lane >> 4;

    const uint4* bq4 = (const uint4*)qw;                 // 2304 uint4
    for (int j4 = t; j4 < 2304; j4 += 256) {
        int row = j4 >> 2, rem = j4 & 3;
        *(uint4*)&lb[row * 20 + rem * 4] = bq4[j4];
    }
    const uint4* qin4 = (const uint4*)qin;
    for (int g4 = t; g4 < 792; g4 += 256) {              // 3 rows x 264 uint4 (px -1..64)
        int ky = g4 / 264, r = g4 - ky * 264;
        int px = r >> 2, rem = r & 3;
        *(uint4*)&lin[(ky * 66 + px) * 20 + rem * 4] =
            qin4[(size_t)(1 + n * ROWS_PI + y + ky) * 256 - 4 + r];
    }
    __syncthreads();

    v4i acc[4] = {{0,0,0,0},{0,0,0,0},{0,0,0,0},{0,0,0,0}};
#pragma unroll
    for (int ky = 0; ky < 3; ky++) {
#pragma unroll
        for (int kx = 0; kx < 3; kx++) {
            int px = w * 16 + mm + kx;                   // lin idx = (x+kx-1)+1
            v4i a = *(const v4i*)&lin[(ky * 66 + px) * 20 + quad * 4];
            int tap = ky * 3 + kx;
#pragma unroll
            for (int nt = 0; nt < 4; nt++) {
                int co = nt * 16 + mm;
                v4i bf = *(const v4i*)&lb[(tap * 64 + co) * 20 + quad * 4];
                acc[nt] = __builtin_amdgcn_mfma_i32_16x16x64_i8(a, bf, acc[nt], 0, 0, 0);
            }
        }
    }
    // epilogue
    float sIn = SECOND ? scal[3] / 255.f : scal[0] / 127.f;
    float sW  = SECOND ? scal[2] / 127.f : scal[1] / 127.f;
    float sx = scal[0] / 127.f;
    float lmax = 0.f;
    size_t rowb = (size_t)(n * 56 + y) * 3584;
    const signed char* idrow = SECOND ? (const signed char*)(qid + (size_t)(2 + n * ROWS_PI + y) * PADROW)
                                      : (const signed char*)nullptr;
#pragma unroll
    for (int nt = 0; nt < 4; nt++) {
        int co = nt * 16 + mm;
        float inv = g[co] * rsqrtf(v[co] + 1e-5f);
        float alpha = sIn * sW * inv;
        float beta = b[co] - m_[co] * inv;
        int wofs = SECOND ? (wsum[co] << 7) : 0;
#pragma unroll
        for (int r = 0; r < 4; r++) {
            int x = w * 16 + quad * 4 + r;
            if (x < 56) {
                float o = (float)(acc[nt][r] + wofs) * alpha + beta;
                if (SECOND) o += sx * (float)idrow[x * 64 + co];
                outp[rowb + x * 64 + co] = o;
                lmax = fmaxf(lmax, o);
            }
        }
    }
    red[t] = lmax; __syncthreads();
    for (int s = 128; s > 0; s >>= 1) {
        if (t < s) red[t] = fmaxf(red[t], red[t + s]);
        __syncthreads();
    }
    if (t == 0) atomicMax((u32*)rmax, __float_as_uint(red[0]));
}

// ---------------- K6: quantize conv1 output -> q1-128 padded int8 ----------------
__global__ __launch_bounds__(256) void k_quant_relu1(const float* __restrict__ of,
                                                     char* __restrict__ qpad,
                                                     const float* __restrict__ scal) {
    int n = blockIdx.x, yy = blockIdx.y, t = threadIdx.x;
    u32* row = (u32*)(qpad + (size_t)(1 + n * ROWS_PI + yy) * PADROW);
    if (n == 0 && yy == 0) {
        u32* r0 = (u32*)qpad;
        for (int j = t; j < 1024; j += 256) r0[j] = 0x80808080u;
    }
    if (yy == 0 || yy == 57) {
        for (int j = t; j < 1024; j += 256) row[j] = 0x80808080u;
        return;
    }
    int y = yy - 1;
    float s1 = scal[3] / 255.f;
    char* rowb = (char*)row;
    const float* orow = of + (size_t)(n * 56 + y) * 3584;
    for (int idx = t; idx < 3584; idx += 256) {
        float vv = fmaxf(orow[idx], 0.f);
        float q = fminf(rintf(vv / s1), 255.f);
        rowb[idx] = (char)((int)q - 128);
    }
    for (int j = 896 + t; j < 1024; j += 256) row[j] = 0x80808080u;
}

// ---------------- K8: final quantize + NHWC->NCHW transpose ----------------
__global__ __launch_bounds__(256) void k_final(const float* __restrict__ of,
                                               const float* __restrict__ scal,
                                               float* __restrict__ outp) {
    int n = blockIdx.x, y = blockIdx.y, t = threadIdx.x;
    __shared__ float lt[64 * 57];
    float s2 = scal[4] / 255.f;
    const float* orow = of + (size_t)(n * 56 + y) * 3584;
    for (int idx = t; idx < 3584; idx += 256) {
        int co = idx & 63, xx = idx >> 6;
        float vv = fmaxf(orow[idx], 0.f);
        float q = fminf(rintf(vv / s2), 255.f);
        lt[co * 57 + xx] = q * s2;
    }
    __syncthreads();
    for (int idx = t; idx < 3584; idx += 256) {
        int co = idx / 56, xx = idx - co * 56;
        outp[(size_t)n * 200704 + (size_t)co * 3136 + y * 56 + xx] = lt[co * 57 + xx];
    }
}

// ---------------- K9: combine bit-stats into HM_act / HM_energy ----------------
__global__ __launch_bounds__(512) void k_hm(const int* __restrict__ stx, const int* __restrict__ stq,
                                            const int* __restrict__ wb1, const int* __restrict__ wb2,
                                            float* __restrict__ outp) {
    int t = threadIdx.x;   // t = ci*8 + k
    long long act = 0, en = 0;
#pragma unroll
    for (int w = 0; w < 2; w++) {
        const int* st = w ? stq : stx;
        const int* wb = w ? wb2 : wb1;
        long long s[9];
#pragma unroll
        for (int j = 0; j < 9; j++) s[j] = st[j * 512 + t];
        const int* wrow = wb + t * 9;
        int w0 = wrow[0], w1_ = wrow[1], w2_ = wrow[2], w3 = wrow[3], w4 = wrow[4],
            w5 = wrow[5], w6 = wrow[6], w7 = wrow[7], w8 = wrow[8];
        long long wall = (long long)w0 + w1_ + w2_ + w3 + w4 + w5 + w6 + w7 + w8;
        long long wr0 = (long long)w0 + w1_ + w2_;
        long long wr2 = (long long)w6 + w7 + w8;
        long long wc0 = (long long)w0 + w3 + w6;
        long long wc2 = (long long)w2_ + w5 + w8;
        en += s[0] * wall - s[1] * wr2 - s[2] * wr0 - s[3] * wc2 - s[4] * wc0
            + s[5] * w8 + s[6] * w6 + s[7] * w2_ + s[8] * w0;
        act += s[0];
    }
    __shared__ long long r1[512];
    r1[t] = en; __syncthreads();
    for (int s = 256; s > 0; s >>= 1) { if (t < s) r1[t] += r1[t + s]; __syncthreads(); }
    long long etot = r1[0]; __syncthreads();
    r1[t] = act; __syncthreads();
    for (int s = 256; s > 0; s >>= 1) { if (t < s) r1[t] += r1[t + s]; __syncthreads(); }
    if (t == 0) {
        outp[OUTN]     = (float)r1[0];   // HM_act
        outp[OUTN + 1] = (float)etot;    // HM_energy
    }
}

extern "C" void kernel_launch(void* const* d_in, const int* in_sizes, int n_in,
                              void* d_out, int out_size, void* d_ws, size_t ws_size,
                              hipStream_t stream) {
    if (ws_size < WS_NEED) return;
    const float* x  = (const float*)d_in[0];
    const float* w1 = (const float*)d_in[1];
    const float* w2 = (const float*)d_in[2];
    const float* g1 = (const float*)d_in[3];
    const float* b1 = (const float*)d_in[4];
    const float* m1 = (const float*)d_in[5];
    const float* v1 = (const float*)d_in[6];
    const float* g2 = (const float*)d_in[7];
    const float* b2 = (const float*)d_in[8];
    const float* m2 = (const float*)d_in[9];
    const float* v2 = (const float*)d_in[10];
    char* ws = (char*)d_ws;
    float* scal = (float*)ws;
    char* qx = ws + OFS_QX;
    char* q1 = ws + OFS_Q1;
    float* o1 = (float*)(ws + OFS_O1);
    float* o2 = (float*)(ws + OFS_O2);
    char* qw1 = ws + OFS_QW1;
    char* qw2 = ws + OFS_QW2;
    int* wb1 = (int*)(ws + OFS_WB1);
    int* wb2 = (int*)(ws + OFS_WB2);
    int* wsum = (int*)(ws + OFS_WSUM);
    int* stx = (int*)(ws + OFS_STX);
    int* stq = (int*)(ws + OFS_STQ);
    float* outp = (float*)d_out;

    k_init<<<18, 256, 0, stream>>>(scal, stx, stq, wsum);
    k_absmax<<<dim3(1024, 3), 256, 0, stream>>>(x, w1, w2, scal);
    k_quant_x<<<dim3(16, 58), 256, 0, stream>>>(x, qx, scal);
    k_quant_w<<<dim3(2, 9), 256, 0, stream>>>(w1, w2, qw1, qw2, wb1, wb2, wsum, scal);
    k_stats<<<dim3(16, 14), 256, 0, stream>>>(qx, 0u, stx);
    k_conv<0><<<dim3(16, 56), 256, 0, stream>>>(qx, qw1, nullptr, nullptr,
                                                g1, b1, m1, v1, scal, o1, scal + 3);
    k_quant_relu1<<<dim3(16, 58), 256, 0, stream>>>(o1, q1, scal);
    k_stats<<<dim3(16, 14), 256, 0, stream>>>(q1, 0x80u, stq);
    k_conv<1><<<dim3(16, 56), 256, 0, stream>>>(q1, qw2, wsum, qx,
                                                g2, b2, m2, v2, scal, o2, scal + 4);
    k_final<<<dim3(16, 56), 256, 0, stream>>>(o2, scal, outp);
    k_hm<<<1, 512, 0, stream>>>(stx, stq, wb1, wb2, outp);
}